// Round 5
// baseline (308.091 us; speedup 1.0000x reference)
//
#include <hip/hip_runtime.h>

// TemplatePointwiseAttention, MI355X/gfx950.
// Folded-weight formulation: G = Z @ Abar (MFMA), 4-way softmax, OUT = S @ Mbar.
// R5 (from R4's confirmed DMA-pipeline win, 287->102us):
//  - Abar moves LDS -> per-wave REGISTER slices (16 x short8/lane). Kills the
//    biggest LDS stream (128 KB/tile GEMM1 B-reads) and frees 64 KB LDS.
//  - sT is now a 3-slot fp32 DMA ring (96 KB): DMA(k+2) issued at X(k), read
//    at Y(k+2) -> ~2 tile-periods in flight, ~64 KB/CU outstanding always.
//  - Retirement chain (R4-proven): GEMM1(k)'s vmcnt wait on z(k) retires all
//    older VMEM incl. DMA(k+1) (in-order vmcnt, m135) => every DMA retired a
//    full phase before its slot is read. Barriers stay {lgkmcnt(0); s_barrier}.
// LDS: sT 3x32K + sG 2x16K = 128 KB (1 block/CU, 8 waves).

#define R_    384
#define P_    (R_ * R_)      // 147456 residue pairs
#define PB    32             // pairs per tile
#define NPB   256            // persistent blocks = CUs
#define NT_   18             // (P_/PB)/NPB

typedef __attribute__((ext_vector_type(8))) short  short8;   // 8 x bf16 MFMA frag
typedef __attribute__((ext_vector_type(4))) float  f32x4;    // MFMA accumulator

union S8U { short8 s8; unsigned u[4]; };

__device__ __forceinline__ unsigned short f2bf(float f) {
  unsigned u = __float_as_uint(f);
  unsigned r = ((u >> 16) & 1u) + 0x7FFFu;   // RNE
  return (unsigned short)((u + r) >> 16);
}
__device__ __forceinline__ float bf2f(unsigned short s) {
  return __uint_as_float(((unsigned)s) << 16);
}
__device__ __forceinline__ unsigned cvtpk(float lo, float hi) {
  unsigned d;
  asm("v_cvt_pk_bf16_f32 %0, %1, %2" : "=v"(d) : "v"(lo), "v"(hi));
  return d;
}
// bf16 LDS tiles [p][c] (p<32, c<256), pitch 256, XOR-swizzled in 16B blocks.
__device__ __forceinline__ int swz(int p, int c) {
  return p * 256 + ((((c >> 3) ^ (p & 31)) << 3) | (c & 7));
}
#define SB() __builtin_amdgcn_sched_barrier(0)
// Raw barrier: LDS drain only — in-flight VMEM (DMA/z prefetch) crosses it.
#define BAR() do { \
    asm volatile("s_waitcnt lgkmcnt(0)\ns_barrier" ::: "memory"); \
    SB(); \
  } while (0)

__device__ __forceinline__ void dma16(const float* g, void* lds) {
  // 16B per lane; LDS dest = wave-uniform base + lane*16 (HW adds lane part).
  __builtin_amdgcn_global_load_lds((const __attribute__((address_space(1))) unsigned*)g,
                                   (__attribute__((address_space(3))) unsigned*)lds,
                                   16, 0, 0);
}

// ---- K0: fold weights into AbarT[n=256][i=128], MbarT[o=128][k=256] (bf16) ----
__global__ void prep_kernel(const float* __restrict__ Wq, const float* __restrict__ Wk,
                            const float* __restrict__ Wv, const float* __restrict__ Wo,
                            unsigned short* __restrict__ AbarT,
                            unsigned short* __restrict__ MbarT) {
  int tid = blockIdx.x * blockDim.x + threadIdx.x;   // 65536 threads
  if (tid < 256 * 128) {
    int n = tid >> 7, i = tid & 127;
    int h = n >> 6, j = n & 63;
    const float* wq = Wq + i * 256 + h * 64;
    const float* wk = Wk + j * 256 + h * 64;
    float acc = 0.f;
#pragma unroll 8
    for (int c = 0; c < 64; ++c) acc += wq[c] * wk[c];
    AbarT[n * 128 + i] = f2bf(acc * 0.125f);         // 1/sqrt(64) folded in
  } else {
    int t2 = tid - 256 * 128;
    int o = t2 >> 8, k = t2 & 255;
    int h = k >> 6, j = k & 63;
    const float* wv = Wv + j * 256 + h * 64;
    const float* wo = Wo + (h * 64) * 128 + o;
    float acc = 0.f;
#pragma unroll 8
    for (int c = 0; c < 64; ++c) acc += wv[c] * wo[c * 128];
    MbarT[o * 256 + k] = f2bf(acc);
  }
}

// ---- persistent fused kernel ----
__global__ __launch_bounds__(512, 2) void attn_kernel(
    const float* __restrict__ z2d, const float* __restrict__ t2d,
    const unsigned short* __restrict__ AbarT, const unsigned short* __restrict__ MbarT,
    const float* __restrict__ bo, float* __restrict__ out) {
  extern __shared__ char smem[];
  float*          sTf = (float*)smem;                       // 3 x [4][32][64] fp32
  unsigned short* sG  = (unsigned short*)(smem + 98304);    // 2 x [32][256] bf16 swz

  const int tid  = threadIdx.x;
  const int wv_  = tid >> 6;
  const int lane = tid & 63;
  const int l = lane & 15;     // MFMA: A row / B col / D col
  const int q = lane >> 4;     // MFMA quad
  const int mt = wv_ & 1;      // m-tile
  const int ng = wv_ >> 1;     // n-group

  // ---- DMA per-lane geometry: wave wv_ covers rows [wv_*4, wv_*4+4) per t.
  // Content swizzle: LDS chunk-slot cs holds global 16B-chunk cs^(p&3).
  const int dp  = wv_ * 4 + (lane >> 4);                    // pair row in tile
  const int dcf = (((lane & 15) ^ ((lane >> 4) & 3)) << 2); // float offset in row

  // ---- attention geometry: thread = (pair ap, head ah, quarter au) ----
  const int ap = tid >> 4, asub = tid & 15;
  const int ah = asub >> 2, au = asub & 3;
  const int aoG0 = swz(ap, ah * 64 + au * 16);
  const int aoG1 = swz(ap, ah * 64 + au * 16 + 8);
  int aoK[4];                                               // float offsets, + t*2048
#pragma unroll
  for (int j = 0; j < 4; ++j)
    aoK[j] = ap * 64 + ((((au * 4 + j) ^ (ap & 3))) << 2);

  const int p2g = mt * 16 + l;                              // GEMM2 A-row

  // ---- Abar -> regs (wave-sliced: 4 n-tiles x 4 kk = 16 short8/lane) ----
  short8 ab[4][4];                                          // [kk][i]
#pragma unroll
  for (int kk = 0; kk < 4; ++kk)
#pragma unroll
    for (int i = 0; i < 4; ++i) {
      const int n = (ng * 4 + i) * 16 + l;
      ab[kk][i] = *(const short8*)(AbarT + n * 128 + kk * 32 + q * 8);
    }
  // ---- Mbar -> regs (wave-sliced: 2 o-tiles x 8 kk) ----
  short8 mb0[8], mb1[8];
#pragma unroll
  for (int kk = 0; kk < 8; ++kk) {
    mb0[kk] = *(const short8*)(MbarT + (size_t)(ng * 32 + l) * 256 + kk * 32 + q * 8);
    mb1[kk] = *(const short8*)(MbarT + (size_t)(ng * 32 + 16 + l) * 256 + kk * 32 + q * 8);
  }
  const float bo0 = bo[ng * 32 + l];
  const float bo1 = bo[ng * 32 + 16 + l];
  SB();
  // ---- DMA(0)->slot0, DMA(1)->slot1, then z(0). Order matters: z(0)'s use at
  //      X(0) retires both DMAs (older) before Y(0)/Y(1) read them. ----
  {
    const size_t P00 = (size_t)blockIdx.x * PB;
    char* dst0 = (char*)sTf + wv_ * 1024;
#pragma unroll
    for (int m = 0; m < 4; ++m)
      dma16(t2d + ((size_t)m * P_ + P00 + dp) * 64 + dcf, dst0 + m * 8192);
    const size_t P01 = P00 + (size_t)NPB * PB;
    char* dst1 = (char*)sTf + 32768 + wv_ * 1024;
#pragma unroll
    for (int m = 0; m < 4; ++m)
      dma16(t2d + ((size_t)m * P_ + P01 + dp) * 64 + dcf, dst1 + m * 8192);
  }
  SB();
  float4 zb[8];
  {
    const float* zr = z2d + ((size_t)blockIdx.x * PB + mt * 16 + l) * 128;
#pragma unroll
    for (int kk = 0; kk < 4; ++kk) {
      zb[2 * kk]     = *(const float4*)(zr + kk * 32 + q * 8);
      zb[2 * kk + 1] = *(const float4*)(zr + kk * 32 + q * 8 + 4);
    }
  }
  BAR();   // DMA(0..1)/z(0) in flight

#pragma unroll 1
  for (int k = 0; k < NT_; ++k) {
    const int slT = (k % 3);
    const int slG = k & 1;
    const size_t P0  = (size_t)(blockIdx.x + (size_t)k * NPB) * PB;
    const size_t P0n = P0 + (size_t)NPB * PB;

    // ======== phase X ========
    // (1) DMA(k+2) -> sT[(k+2)%3]  (read at Y(k+2): ~2 tile-periods in flight)
    if (k + 2 < NT_) {
      char* dst = (char*)sTf + ((k + 2) % 3) * 32768 + wv_ * 1024;
      const size_t P02 = P0 + 2 * (size_t)NPB * PB;
#pragma unroll
      for (int m = 0; m < 4; ++m)
        dma16(t2d + ((size_t)m * P_ + P02 + dp) * 64 + dcf, dst + m * 8192);
    }
    SB();
    // (2) GEMM2 tile k-1: S(sG[slG^1]) @ Mbar(regs) -> out
    if (k > 0) {
      const unsigned short* sGp = sG + (slG ^ 1) * 8192;
      f32x4 a20 = f32x4{0.f, 0.f, 0.f, 0.f};
      f32x4 a21 = f32x4{0.f, 0.f, 0.f, 0.f};
#pragma unroll
      for (int kk = 0; kk < 8; ++kk) {
        short8 af2 = *(const short8*)(sGp + p2g * 256 + (((kk * 4 + q) ^ p2g) << 3));
        a20 = __builtin_amdgcn_mfma_f32_16x16x32_bf16(af2, mb0[kk], a20, 0, 0, 0);
        a21 = __builtin_amdgcn_mfma_f32_16x16x32_bf16(af2, mb1[kk], a21, 0, 0, 0);
      }
      const size_t rb = (P0 - (size_t)NPB * PB + (size_t)(mt * 16 + q * 4)) * 128;
#pragma unroll
      for (int r = 0; r < 4; ++r) {
        out[rb + r * 128 + ng * 32 + l]      = a20[r] + bo0;
        out[rb + r * 128 + ng * 32 + 16 + l] = a21[r] + bo1;
      }
    }
    SB();
    // (3) GEMM1 tile k: af=cvt(zb) — the vmcnt wait here retires z(k) and (in
    //     order) all older DMA. Pure-register MFMA vs ab[][]; G -> sG[slG].
    {
      f32x4 a1[4];
#pragma unroll
      for (int i = 0; i < 4; ++i) a1[i] = f32x4{0.f, 0.f, 0.f, 0.f};
#pragma unroll
      for (int kk = 0; kk < 4; ++kk) {
        S8U af;
        af.u[0] = cvtpk(zb[2 * kk].x,     zb[2 * kk].y);
        af.u[1] = cvtpk(zb[2 * kk].z,     zb[2 * kk].w);
        af.u[2] = cvtpk(zb[2 * kk + 1].x, zb[2 * kk + 1].y);
        af.u[3] = cvtpk(zb[2 * kk + 1].z, zb[2 * kk + 1].w);
#pragma unroll
        for (int i = 0; i < 4; ++i)
          a1[i] = __builtin_amdgcn_mfma_f32_16x16x32_bf16(af.s8, ab[kk][i], a1[i], 0, 0, 0);
      }
      unsigned short* sGc = sG + slG * 8192;
#pragma unroll
      for (int i = 0; i < 4; ++i) {
        const int c = (ng * 4 + i) * 16 + l;
#pragma unroll
        for (int r = 0; r < 4; ++r)
          sGc[swz(mt * 16 + q * 4 + r, c)] = f2bf(a1[i][r]);  // m89-verified D layout
      }
    }
    SB();
    // (4) z(k+1) -> zb (issued last; in flight across Y(k))
    if (k + 1 < NT_) {
      const float* zr = z2d + (P0n + (size_t)(mt * 16 + l)) * 128;
#pragma unroll
      for (int kk = 0; kk < 4; ++kk) {
        zb[2 * kk]     = *(const float4*)(zr + kk * 32 + q * 8);
        zb[2 * kk + 1] = *(const float4*)(zr + kk * 32 + q * 8 + 4);
      }
    }
    SB();
    BAR();

    // ======== phase Y: attention ========
    {
      const float* Kt = sTf + slT * 8192;               // [4][32][64] fp32, chunk-swz
      unsigned short* sGc = sG + slG * 8192;
      short8 g0 = *(const short8*)(sGc + aoG0);
      short8 g1 = *(const short8*)(sGc + aoG1);
      float lg0 = 0.f, lg1 = 0.f, lg2 = 0.f, lg3 = 0.f;
#pragma unroll
      for (int j = 0; j < 4; ++j) {
        const float ga = bf2f((unsigned short)((j < 2) ? g0[4 * j]     : g1[4 * (j - 2)]));
        const float gb = bf2f((unsigned short)((j < 2) ? g0[4 * j + 1] : g1[4 * (j - 2) + 1]));
        const float gc = bf2f((unsigned short)((j < 2) ? g0[4 * j + 2] : g1[4 * (j - 2) + 2]));
        const float gd = bf2f((unsigned short)((j < 2) ? g0[4 * j + 3] : g1[4 * (j - 2) + 3]));
        float4 k0 = *(const float4*)(Kt +        aoK[j]);
        float4 k1 = *(const float4*)(Kt + 2048 + aoK[j]);
        float4 k2 = *(const float4*)(Kt + 4096 + aoK[j]);
        float4 k3 = *(const float4*)(Kt + 6144 + aoK[j]);
        lg0 += ga * k0.x + gb * k0.y + gc * k0.z + gd * k0.w;
        lg1 += ga * k1.x + gb * k1.y + gc * k1.z + gd * k1.w;
        lg2 += ga * k2.x + gb * k2.y + gc * k2.z + gd * k2.w;
        lg3 += ga * k3.x + gb * k3.y + gc * k3.z + gd * k3.w;
      }
      lg0 += __shfl_xor(lg0, 1); lg0 += __shfl_xor(lg0, 2);
      lg1 += __shfl_xor(lg1, 1); lg1 += __shfl_xor(lg1, 2);
      lg2 += __shfl_xor(lg2, 1); lg2 += __shfl_xor(lg2, 2);
      lg3 += __shfl_xor(lg3, 1); lg3 += __shfl_xor(lg3, 2);
      const float mx = fmaxf(fmaxf(lg0, lg1), fmaxf(lg2, lg3));
      float e0 = __expf(lg0 - mx), e1 = __expf(lg1 - mx);
      float e2 = __expf(lg2 - mx), e3 = __expf(lg3 - mx);
      const float inv = 1.f / (e0 + e1 + e2 + e3);
      e0 *= inv; e1 *= inv; e2 *= inv; e3 *= inv;
      // S[ap][ah*64+au*16+j*4 ..+4) = sum_t e_t * K_t  (own slice, in place)
#pragma unroll
      for (int j = 0; j < 4; ++j) {
        float4 k0 = *(const float4*)(Kt +        aoK[j]);
        float4 k1 = *(const float4*)(Kt + 2048 + aoK[j]);
        float4 k2 = *(const float4*)(Kt + 4096 + aoK[j]);
        float4 k3 = *(const float4*)(Kt + 6144 + aoK[j]);
        float s0 = e0 * k0.x + e1 * k1.x + e2 * k2.x + e3 * k3.x;
        float s1 = e0 * k0.y + e1 * k1.y + e2 * k2.y + e3 * k3.y;
        float s2 = e0 * k0.z + e1 * k1.z + e2 * k2.z + e3 * k3.z;
        float s3 = e0 * k0.w + e1 * k1.w + e2 * k2.w + e3 * k3.w;
        uint2 w2; w2.x = cvtpk(s0, s1); w2.y = cvtpk(s2, s3);
        *(uint2*)(sGc + swz(ap, ah * 64 + au * 16 + j * 4)) = w2;   // 8B, aligned
      }
    }
    BAR();
  }

  // ---- tail: GEMM2 for the last tile (slG of NT_-1 = 1) ----
  {
    const unsigned short* sGp = sG + 8192;
    f32x4 a20 = f32x4{0.f, 0.f, 0.f, 0.f};
    f32x4 a21 = f32x4{0.f, 0.f, 0.f, 0.f};
#pragma unroll
    for (int kk = 0; kk < 8; ++kk) {
      short8 af2 = *(const short8*)(sGp + p2g * 256 + (((kk * 4 + q) ^ p2g) << 3));
      a20 = __builtin_amdgcn_mfma_f32_16x16x32_bf16(af2, mb0[kk], a20, 0, 0, 0);
      a21 = __builtin_amdgcn_mfma_f32_16x16x32_bf16(af2, mb1[kk], a21, 0, 0, 0);
    }
    const size_t rb = ((size_t)(blockIdx.x + (size_t)(NT_ - 1) * NPB) * PB
                       + (size_t)(mt * 16 + q * 4)) * 128;
#pragma unroll
    for (int r = 0; r < 4; ++r) {
      out[rb + r * 128 + ng * 32 + l]      = a20[r] + bo0;
      out[rb + r * 128 + ng * 32 + 16 + l] = a21[r] + bo1;
    }
  }
}

extern "C" void kernel_launch(void* const* d_in, const int* in_sizes, int n_in,
                              void* d_out, int out_size, void* d_ws, size_t ws_size,
                              hipStream_t stream) {
  const float* z2d = (const float*)d_in[0];
  const float* t2d = (const float*)d_in[1];
  const float* Wq  = (const float*)d_in[2];
  const float* Wk  = (const float*)d_in[3];
  const float* Wv  = (const float*)d_in[4];
  const float* Wo  = (const float*)d_in[5];
  const float* bo  = (const float*)d_in[6];

  unsigned short* AbarT = (unsigned short*)d_ws;           // 256*128 bf16 = 64 KB
  unsigned short* MbarT = AbarT + 256 * 128;               // 128*256 bf16 = 64 KB
  float* out = (float*)d_out;

  static bool attr_set = false;
  if (!attr_set) {
    (void)hipFuncSetAttribute((const void*)attn_kernel,
                              hipFuncAttributeMaxDynamicSharedMemorySize, 131072);
    attr_set = true;
  }

  hipLaunchKernelGGL(prep_kernel, dim3(256), dim3(256), 0, stream,
                     Wq, Wk, Wv, Wo, AbarT, MbarT);
  hipLaunchKernelGGL(attn_kernel, dim3(NPB), dim3(512), 131072, stream,
                     z2d, t2d, AbarT, MbarT, bo, out);
}

// Round 6
// 304.735 us; speedup vs baseline: 1.0110x; 1.0110x over previous
//
#include <hip/hip_runtime.h>

// TemplatePointwiseAttention, MI355X/gfx950.
// Folded-weight formulation: G = Z @ Abar (MFMA), 4-way softmax, OUT = S @ Mbar.
// R6: de-lockstep. PB=16, 256 threads (4 waves = 4 heads), 512 blocks
// (2 blocks/CU = 2 independent barrier domains), 18 tiles/block.
// ONE barrier per tile: wave ng computes G1 for all 16 rows x head-ng cols,
// so G1->attention is wave-local (lgkmcnt only); only attention->G2 (reduces
// over all heads' S) needs s_barrier. DMA: 4-slot sT ring, distance 3, issued
// post-attention. Cross-wave DMA retirement: DMA(m) [iter m-3] is older than
// z(m-2) [iter m-2], so each wave's compiler zb-wait at G1(m-1) retires it
// before BAR(m-1) < any attn(m) read. Prologue: one-time vmcnt(8)+barrier.
// LDS/block: sT 4x16K + sG 2x8K = 80 KB -> exactly 2 blocks/CU.

#define R_    384
#define P_    (R_ * R_)      // 147456 residue pairs
#define PB    16             // pairs per tile
#define NPB   512            // blocks (2 per CU)
#define NT_   18             // tiles per block

typedef __attribute__((ext_vector_type(8))) short  short8;   // 8 x bf16 MFMA frag
typedef __attribute__((ext_vector_type(4))) float  f32x4;    // MFMA accumulator

union S8U { short8 s8; unsigned u[4]; };

__device__ __forceinline__ unsigned short f2bf(float f) {
  unsigned u = __float_as_uint(f);
  unsigned r = ((u >> 16) & 1u) + 0x7FFFu;   // RNE
  return (unsigned short)((u + r) >> 16);
}
__device__ __forceinline__ float bf2f(unsigned short s) {
  return __uint_as_float(((unsigned)s) << 16);
}
__device__ __forceinline__ unsigned cvtpk(float lo, float hi) {
  unsigned d;
  asm("v_cvt_pk_bf16_f32 %0, %1, %2" : "=v"(d) : "v"(lo), "v"(hi));
  return d;
}
// bf16 LDS tile [p][c] (p<16, c<256), pitch 256, XOR-swizzled 16B blocks.
__device__ __forceinline__ int swz16(int p, int c) {
  return p * 256 + ((((c >> 3) ^ p) << 3) | (c & 7));
}
#define SB() __builtin_amdgcn_sched_barrier(0)
// Raw barrier: LDS drain only — in-flight VMEM (DMA/z prefetch) crosses it.
#define BAR() do { \
    asm volatile("s_waitcnt lgkmcnt(0)\ns_barrier" ::: "memory"); \
    SB(); \
  } while (0)

__device__ __forceinline__ void dma16(const float* g, void* lds) {
  // 16B per lane; LDS dest = wave-uniform base + lane*16 (HW adds lane part).
  __builtin_amdgcn_global_load_lds((const __attribute__((address_space(1))) unsigned*)g,
                                   (__attribute__((address_space(3))) unsigned*)lds,
                                   16, 0, 0);
}

// ---- K0: fold weights into AbarT[n=256][i=128], MbarT[o=128][k=256] (bf16) ----
__global__ void prep_kernel(const float* __restrict__ Wq, const float* __restrict__ Wk,
                            const float* __restrict__ Wv, const float* __restrict__ Wo,
                            unsigned short* __restrict__ AbarT,
                            unsigned short* __restrict__ MbarT) {
  int tid = blockIdx.x * blockDim.x + threadIdx.x;   // 65536 threads
  if (tid < 256 * 128) {
    int n = tid >> 7, i = tid & 127;
    int h = n >> 6, j = n & 63;
    const float* wq = Wq + i * 256 + h * 64;
    const float* wk = Wk + j * 256 + h * 64;
    float acc = 0.f;
#pragma unroll 8
    for (int c = 0; c < 64; ++c) acc += wq[c] * wk[c];
    AbarT[n * 128 + i] = f2bf(acc * 0.125f);         // 1/sqrt(64) folded in
  } else {
    int t2 = tid - 256 * 128;
    int o = t2 >> 8, k = t2 & 255;
    int h = k >> 6, j = k & 63;
    const float* wv = Wv + j * 256 + h * 64;
    const float* wo = Wo + (h * 64) * 128 + o;
    float acc = 0.f;
#pragma unroll 8
    for (int c = 0; c < 64; ++c) acc += wv[c] * wo[c * 128];
    MbarT[o * 256 + k] = f2bf(acc);
  }
}

// ---- persistent fused kernel ----
__global__ __launch_bounds__(256, 2) void attn_kernel(
    const float* __restrict__ z2d, const float* __restrict__ t2d,
    const unsigned short* __restrict__ AbarT, const unsigned short* __restrict__ MbarT,
    const float* __restrict__ bo, float* __restrict__ out) {
  extern __shared__ char smem[];
  float*          sTf = (float*)smem;                     // 4 x [4t][16p][64c] fp32 (64 KB)
  unsigned short* sG  = (unsigned short*)(smem + 65536);  // 2 x [16][256] bf16 swz (16 KB)

  const int tid  = threadIdx.x;
  const int ng   = tid >> 6;   // wave id = head = GEMM1 col-group = GEMM2 o-group
  const int lane = tid & 63;
  const int l = lane & 15;     // MFMA A row / B col / D col; attn pair
  const int q = lane >> 4;     // MFMA quad; attn quarter

  // ---- weights -> regs (wave-sliced) ----
  short8 ab[4][4];             // Abar: [kk][i], cols (ng*4+i)*16+l
#pragma unroll
  for (int kk = 0; kk < 4; ++kk)
#pragma unroll
    for (int i = 0; i < 4; ++i)
      ab[kk][i] = *(const short8*)(AbarT + ((ng * 4 + i) * 16 + l) * 128 + kk * 32 + q * 8);
  short8 mb0[8], mb1[8];       // Mbar: o-tiles ng*2, ng*2+1
#pragma unroll
  for (int kk = 0; kk < 8; ++kk) {
    mb0[kk] = *(const short8*)(MbarT + (size_t)((ng * 2) * 16 + l) * 256 + kk * 32 + q * 8);
    mb1[kk] = *(const short8*)(MbarT + (size_t)((ng * 2 + 1) * 16 + l) * 256 + kk * 32 + q * 8);
  }
  const float bo0 = bo[ng * 32 + l];
  const float bo1 = bo[ng * 32 + 16 + l];
  SB();

  // ---- prologue: DMA slots 0..2, then z(0); vmcnt(8) keeps z, drains DMAs ----
#pragma unroll
  for (int s = 0; s < 3; ++s) {
    const size_t P0s = (size_t)(blockIdx.x + s * NPB) * PB;
    char* dst = (char*)sTf + s * 16384 + ng * 4096;
#pragma unroll
    for (int m = 0; m < 4; ++m) {
      const int dp  = m * 4 + q;                       // pair row (this lane's quad)
      const int dcf = (l ^ (((m & 1) << 2) | q)) << 2; // chunk swizzle ^(dp&7)
      dma16(t2d + ((size_t)ng * P_ + P0s + dp) * 64 + dcf, dst + m * 1024);
    }
  }
  SB();
  float4 zb[8];
  {
    const float* zr = z2d + ((size_t)blockIdx.x * PB + l) * 128;
#pragma unroll
    for (int kk = 0; kk < 4; ++kk) {
      zb[2 * kk]     = *(const float4*)(zr + kk * 32 + q * 8);
      zb[2 * kk + 1] = *(const float4*)(zr + kk * 32 + q * 8 + 4);
    }
  }
  SB();
  asm volatile("s_waitcnt vmcnt(8)" ::: "memory");  // slots 0..2 arrived; z(0) in flight
  SB();
  BAR();

#pragma unroll 1
  for (int k = 0; k < NT_; ++k) {
    const size_t P0 = (size_t)(blockIdx.x + (size_t)k * NPB) * PB;

    // (1) GEMM2 tile k-1: S(sG[(k-1)&1]) @ Mbar(regs) -> out
    if (k > 0) {
      const unsigned short* sGp = sG + ((k - 1) & 1) * 4096;
      f32x4 a20 = f32x4{0.f, 0.f, 0.f, 0.f};
      f32x4 a21 = f32x4{0.f, 0.f, 0.f, 0.f};
#pragma unroll
      for (int kk = 0; kk < 8; ++kk) {
        short8 af2 = *(const short8*)(sGp + l * 256 + (((kk * 4 + q) ^ l) << 3));
        a20 = __builtin_amdgcn_mfma_f32_16x16x32_bf16(af2, mb0[kk], a20, 0, 0, 0);
        a21 = __builtin_amdgcn_mfma_f32_16x16x32_bf16(af2, mb1[kk], a21, 0, 0, 0);
      }
      const size_t rb = ((size_t)(blockIdx.x + (size_t)(k - 1) * NPB) * PB + q * 4) * 128;
#pragma unroll
      for (int r = 0; r < 4; ++r) {
        out[rb + r * 128 + ng * 32 + l]      = a20[r] + bo0;
        out[rb + r * 128 + ng * 32 + 16 + l] = a21[r] + bo1;
      }
    }
    SB();
    // (2) GEMM1 tile k: compiler's vmcnt wait for zb(k) retires all older VMEM
    //     (incl. DMA(k+1), DMA(k+2) cross-tile chain). G -> sG[k&1], own cols.
    {
      f32x4 a1[4];
#pragma unroll
      for (int i = 0; i < 4; ++i) a1[i] = f32x4{0.f, 0.f, 0.f, 0.f};
#pragma unroll
      for (int kk = 0; kk < 4; ++kk) {
        S8U af;
        af.u[0] = cvtpk(zb[2 * kk].x,     zb[2 * kk].y);
        af.u[1] = cvtpk(zb[2 * kk].z,     zb[2 * kk].w);
        af.u[2] = cvtpk(zb[2 * kk + 1].x, zb[2 * kk + 1].y);
        af.u[3] = cvtpk(zb[2 * kk + 1].z, zb[2 * kk + 1].w);
#pragma unroll
        for (int i = 0; i < 4; ++i)
          a1[i] = __builtin_amdgcn_mfma_f32_16x16x32_bf16(af.s8, ab[kk][i], a1[i], 0, 0, 0);
      }
      unsigned short* sGc = sG + (k & 1) * 4096;
#pragma unroll
      for (int i = 0; i < 4; ++i) {
        const int c = ng * 64 + i * 16 + l;
#pragma unroll
        for (int r = 0; r < 4; ++r)
          sGc[swz16(q * 4 + r, c)] = f2bf(a1[i][r]);   // m89-verified D layout
      }
    }
    SB();
    // (3) z(k+1) -> zb (after G1's last zb read; in flight across attn+BAR+G2)
    if (k + 1 < NT_) {
      const float* zr = z2d + (P0 + (size_t)NPB * PB + l) * 128;
#pragma unroll
      for (int kk = 0; kk < 4; ++kk) {
        zb[2 * kk]     = *(const float4*)(zr + kk * 32 + q * 8);
        zb[2 * kk + 1] = *(const float4*)(zr + kk * 32 + q * 8 + 4);
      }
    }
    SB();
    // (4) wave-local: own G1 writes visible to own attention reads
    asm volatile("s_waitcnt lgkmcnt(0)" ::: "memory");
    SB();
    // (5) attention tile k: pair p=l, quarter u=q, head ng (all wave-local G)
    {
      const float* Kt = sTf + (k & 3) * 4096;          // [4t][16p][64c] fp32, swz
      unsigned short* sGc = sG + (k & 1) * 4096;
      short8 g0 = *(const short8*)(sGc + swz16(l, ng * 64 + q * 16));
      short8 g1 = *(const short8*)(sGc + swz16(l, ng * 64 + q * 16 + 8));
      int aoK[4];
#pragma unroll
      for (int j = 0; j < 4; ++j)
        aoK[j] = l * 64 + (((q * 4 + j) ^ (l & 7)) << 2);
      float lg0 = 0.f, lg1 = 0.f, lg2 = 0.f, lg3 = 0.f;
#pragma unroll
      for (int j = 0; j < 4; ++j) {
        const float ga = bf2f((unsigned short)((j < 2) ? g0[4 * j]     : g1[4 * (j - 2)]));
        const float gb = bf2f((unsigned short)((j < 2) ? g0[4 * j + 1] : g1[4 * (j - 2) + 1]));
        const float gc = bf2f((unsigned short)((j < 2) ? g0[4 * j + 2] : g1[4 * (j - 2) + 2]));
        const float gd = bf2f((unsigned short)((j < 2) ? g0[4 * j + 3] : g1[4 * (j - 2) + 3]));
        float4 k0 = *(const float4*)(Kt +        aoK[j]);
        float4 k1 = *(const float4*)(Kt + 1024 + aoK[j]);
        float4 k2 = *(const float4*)(Kt + 2048 + aoK[j]);
        float4 k3 = *(const float4*)(Kt + 3072 + aoK[j]);
        lg0 += ga * k0.x + gb * k0.y + gc * k0.z + gd * k0.w;
        lg1 += ga * k1.x + gb * k1.y + gc * k1.z + gd * k1.w;
        lg2 += ga * k2.x + gb * k2.y + gc * k2.z + gd * k2.w;
        lg3 += ga * k3.x + gb * k3.y + gc * k3.z + gd * k3.w;
      }
      // combine quarters: lanes l, l+16, l+32, l+48
      lg0 += __shfl_xor(lg0, 16); lg0 += __shfl_xor(lg0, 32);
      lg1 += __shfl_xor(lg1, 16); lg1 += __shfl_xor(lg1, 32);
      lg2 += __shfl_xor(lg2, 16); lg2 += __shfl_xor(lg2, 32);
      lg3 += __shfl_xor(lg3, 16); lg3 += __shfl_xor(lg3, 32);
      const float mx = fmaxf(fmaxf(lg0, lg1), fmaxf(lg2, lg3));
      float e0 = __expf(lg0 - mx), e1 = __expf(lg1 - mx);
      float e2 = __expf(lg2 - mx), e3 = __expf(lg3 - mx);
      const float inv = 1.f / (e0 + e1 + e2 + e3);
      e0 *= inv; e1 *= inv; e2 *= inv; e3 *= inv;
      asm volatile("" ::: "memory");   // force K re-read (keep VGPR peak low)
#pragma unroll
      for (int j = 0; j < 4; ++j) {
        float4 k0 = *(const float4*)(Kt +        aoK[j]);
        float4 k1 = *(const float4*)(Kt + 1024 + aoK[j]);
        float4 k2 = *(const float4*)(Kt + 2048 + aoK[j]);
        float4 k3 = *(const float4*)(Kt + 3072 + aoK[j]);
        float s0 = e0 * k0.x + e1 * k1.x + e2 * k2.x + e3 * k3.x;
        float s1 = e0 * k0.y + e1 * k1.y + e2 * k2.y + e3 * k3.y;
        float s2 = e0 * k0.z + e1 * k1.z + e2 * k2.z + e3 * k3.z;
        float s3 = e0 * k0.w + e1 * k1.w + e2 * k2.w + e3 * k3.w;
        uint2 w2; w2.x = cvtpk(s0, s1); w2.y = cvtpk(s2, s3);
        *(uint2*)(sGc + swz16(l, ng * 64 + q * 16 + 4 * j)) = w2;   // 8B aligned
      }
    }
    SB();
    // (6) DMA(k+3) -> sT[(k+3)&3], post-attn (newer than z(k+1): retired by
    //     every wave's zb(k+2) wait at G1(k+2), before BAR(k+2) < attn(k+3))
    if (k + 3 < NT_) {
      const size_t P03 = P0 + 3 * (size_t)NPB * PB;
      char* dst = (char*)sTf + ((k + 3) & 3) * 16384 + ng * 4096;
#pragma unroll
      for (int m = 0; m < 4; ++m) {
        const int dp  = m * 4 + q;
        const int dcf = (l ^ (((m & 1) << 2) | q)) << 2;
        dma16(t2d + ((size_t)ng * P_ + P03 + dp) * 64 + dcf, dst + m * 1024);
      }
    }
    SB();
    BAR();
  }

  // ---- tail: GEMM2 for the last tile ----
  {
    const unsigned short* sGp = sG + ((NT_ - 1) & 1) * 4096;
    f32x4 a20 = f32x4{0.f, 0.f, 0.f, 0.f};
    f32x4 a21 = f32x4{0.f, 0.f, 0.f, 0.f};
#pragma unroll
    for (int kk = 0; kk < 8; ++kk) {
      short8 af2 = *(const short8*)(sGp + l * 256 + (((kk * 4 + q) ^ l) << 3));
      a20 = __builtin_amdgcn_mfma_f32_16x16x32_bf16(af2, mb0[kk], a20, 0, 0, 0);
      a21 = __builtin_amdgcn_mfma_f32_16x16x32_bf16(af2, mb1[kk], a21, 0, 0, 0);
    }
    const size_t rb = ((size_t)(blockIdx.x + (size_t)(NT_ - 1) * NPB) * PB + q * 4) * 128;
#pragma unroll
    for (int r = 0; r < 4; ++r) {
      out[rb + r * 128 + ng * 32 + l]      = a20[r] + bo0;
      out[rb + r * 128 + ng * 32 + 16 + l] = a21[r] + bo1;
    }
  }
}

extern "C" void kernel_launch(void* const* d_in, const int* in_sizes, int n_in,
                              void* d_out, int out_size, void* d_ws, size_t ws_size,
                              hipStream_t stream) {
  const float* z2d = (const float*)d_in[0];
  const float* t2d = (const float*)d_in[1];
  const float* Wq  = (const float*)d_in[2];
  const float* Wk  = (const float*)d_in[3];
  const float* Wv  = (const float*)d_in[4];
  const float* Wo  = (const float*)d_in[5];
  const float* bo  = (const float*)d_in[6];

  unsigned short* AbarT = (unsigned short*)d_ws;           // 256*128 bf16 = 64 KB
  unsigned short* MbarT = AbarT + 256 * 128;               // 128*256 bf16 = 64 KB
  float* out = (float*)d_out;

  static bool attr_set = false;
  if (!attr_set) {
    (void)hipFuncSetAttribute((const void*)attn_kernel,
                              hipFuncAttributeMaxDynamicSharedMemorySize, 81920);
    attr_set = true;
  }

  hipLaunchKernelGGL(prep_kernel, dim3(256), dim3(256), 0, stream,
                     Wq, Wk, Wv, Wo, AbarT, MbarT);
  hipLaunchKernelGGL(attn_kernel, dim3(NPB), dim3(256), 81920, stream,
                     z2d, t2d, AbarT, MbarT, bo, out);
}